// Round 1
// baseline (139.572 us; speedup 1.0000x reference)
//
#include <hip/hip_runtime.h>
#include <hip/hip_bf16.h>
#include <math.h>

#define N_TOK 8192
#define D_IN  768
#define D_OUT 64

typedef __attribute__((ext_vector_type(8))) short short8;
typedef __attribute__((ext_vector_type(4))) short short4v;
typedef __attribute__((ext_vector_type(4))) float f32x4;

// f32 -> bf16 bits, round-to-nearest-even (no NaN inputs here)
__device__ __forceinline__ short f2bf(float f) {
  union { float f; unsigned u; } v; v.f = f;
  unsigned r = v.u + 0x7fffu + ((v.u >> 16) & 1u);
  return (short)(r >> 16);
}

// ---------------------------------------------------------------------------
// Projection: per blockIdx.y in {0,1,2} compute X @ W_{q,k,v} for a 64-row tile.
//   which==0: Q, pre-scaled by log2(e)/8 (folds softmax scale + exp->exp2)
//   which==1: K, row-major bf16
//   which==2: V stored transposed Vt[d][n] so PV B-frags are contiguous
// ---------------------------------------------------------------------------
__global__ __launch_bounds__(256) void proj_kernel(
    const float* __restrict__ X,
    const float* __restrict__ Wq, const float* __restrict__ Wk,
    const float* __restrict__ Wv,
    short* __restrict__ Q, short* __restrict__ K, short* __restrict__ Vt)
{
  __shared__ short Xs[64][40];   // stride 40 shorts = 80B: 16B-aligned rows, ~2-way banks (free)
  __shared__ short Ws[64][40];   // Wt: [col][k]

  const int t  = threadIdx.x;
  const int w  = t >> 6;         // wave id 0..3
  const int l  = t & 63;
  const int g  = l >> 4;         // lane group 0..3
  const int lr = l & 15;
  const int which = blockIdx.y;
  const float* W = (which == 0) ? Wq : (which == 1) ? Wk : Wv;
  const int r0 = blockIdx.x * 64;

  f32x4 acc[4] = {};

  for (int kb = 0; kb < D_IN; kb += 32) {
    // stage X tile [64][32] -> bf16
    {
      const int row = t >> 2, kc = (t & 3) * 8;
      const float* src = X + (size_t)(r0 + row) * D_IN + kb + kc;
      short8 v;
      #pragma unroll
      for (int i = 0; i < 8; ++i) v[i] = f2bf(src[i]);
      *reinterpret_cast<short8*>(&Xs[row][kc]) = v;
    }
    // stage W^T tile: Ws[col][k] = W[kb+k][col]
    {
      const int col = t & 63, k0 = (t >> 6) * 8;
      #pragma unroll
      for (int i = 0; i < 8; ++i)
        Ws[col][k0 + i] = f2bf(W[(size_t)(kb + k0 + i) * D_OUT + col]);
    }
    __syncthreads();

    short8 a = *reinterpret_cast<const short8*>(&Xs[w * 16 + lr][g * 8]);
    #pragma unroll
    for (int dt = 0; dt < 4; ++dt) {
      short8 b = *reinterpret_cast<const short8*>(&Ws[dt * 16 + lr][g * 8]);
      acc[dt] = __builtin_amdgcn_mfma_f32_16x16x32_bf16(a, b, acc[dt], 0, 0, 0);
    }
    __syncthreads();
  }

  // C/D layout: col = lane&15 (within dt tile), row = g*4 + r
  const int rb = r0 + w * 16 + g * 4;
  if (which == 0) {
    const float QS = 0.18033688011112042f;  // log2(e) / sqrt(64)
    #pragma unroll
    for (int dt = 0; dt < 4; ++dt)
      #pragma unroll
      for (int r = 0; r < 4; ++r)
        Q[(size_t)(rb + r) * D_OUT + dt * 16 + lr] = f2bf(acc[dt][r] * QS);
  } else if (which == 1) {
    #pragma unroll
    for (int dt = 0; dt < 4; ++dt)
      #pragma unroll
      for (int r = 0; r < 4; ++r)
        K[(size_t)(rb + r) * D_OUT + dt * 16 + lr] = f2bf(acc[dt][r]);
  } else {
    #pragma unroll
    for (int dt = 0; dt < 4; ++dt) {
      short4v pv;
      #pragma unroll
      for (int r = 0; r < 4; ++r) pv[r] = f2bf(acc[dt][r]);
      *reinterpret_cast<short4v*>(&Vt[(size_t)(dt * 16 + lr) * N_TOK + rb]) = pv;
    }
  }
}

// ---------------------------------------------------------------------------
// Flash attention: block = 16 q-rows, 4 waves split the 8192 KV rows 4-way
// (2048 each, KVBLK=32), online softmax per wave, LDS merge at the end.
// Scores already folded: s' = (q.k)/8 * log2(e)  ->  p = exp2(s' - m')
// ---------------------------------------------------------------------------
__global__ __launch_bounds__(256) void attn_kernel(
    const short* __restrict__ Q, const short* __restrict__ K,
    const short* __restrict__ Vt, float* __restrict__ out)
{
  __shared__ short Pb[4][16][40];       // per-wave P tile, padded stride
  __shared__ float Opart[4][16][64];
  __shared__ float mpart[4][16];
  __shared__ float lpart[4][16];

  const int t  = threadIdx.x;
  const int w  = t >> 6;
  const int l  = t & 63;
  const int g  = l >> 4;
  const int lr = l & 15;
  const int q0 = blockIdx.x * 16;

  // Q A-frags (row = lane&15, k-chunk = g*8)
  const short* qp = Q + (size_t)(q0 + lr) * D_OUT + g * 8;
  short8 aq0 = *reinterpret_cast<const short8*>(qp);
  short8 aq1 = *reinterpret_cast<const short8*>(qp + 32);

  float m[4], lsum[4];
  f32x4 o[4] = {};
  #pragma unroll
  for (int r = 0; r < 4; ++r) { m[r] = -INFINITY; lsum[r] = 0.0f; }

  const int kv0 = w * (N_TOK / 4);

  for (int it = 0; it < (N_TOK / 4) / 32; ++it) {
    const int kvb = kv0 + it * 32;

    // S = Q K^T for 32 kv rows (jt = 0,1)
    f32x4 s[2] = {};
    #pragma unroll
    for (int jt = 0; jt < 2; ++jt) {
      const short* kp = K + (size_t)(kvb + jt * 16 + lr) * D_OUT + g * 8;
      short8 b0 = *reinterpret_cast<const short8*>(kp);
      short8 b1 = *reinterpret_cast<const short8*>(kp + 32);
      s[jt] = __builtin_amdgcn_mfma_f32_16x16x32_bf16(aq0, b0, s[jt], 0, 0, 0);
      s[jt] = __builtin_amdgcn_mfma_f32_16x16x32_bf16(aq1, b1, s[jt], 0, 0, 0);
    }

    // online softmax per q-row (rows owned: g*4 + r)
    float scale_[4];
    #pragma unroll
    for (int r = 0; r < 4; ++r) {
      float mx = fmaxf(s[0][r], s[1][r]);
      mx = fmaxf(mx, __shfl_xor(mx, 1));
      mx = fmaxf(mx, __shfl_xor(mx, 2));
      mx = fmaxf(mx, __shfl_xor(mx, 4));
      mx = fmaxf(mx, __shfl_xor(mx, 8));
      const float mnew = fmaxf(m[r], mx);
      scale_[r] = exp2f(m[r] - mnew);           // first iter: exp2(-inf) = 0
      m[r] = mnew;
      const float p0 = exp2f(s[0][r] - mnew);
      const float p1 = exp2f(s[1][r] - mnew);
      s[0][r] = p0; s[1][r] = p1;
      float ps = p0 + p1;
      ps += __shfl_xor(ps, 1);
      ps += __shfl_xor(ps, 2);
      ps += __shfl_xor(ps, 4);
      ps += __shfl_xor(ps, 8);
      lsum[r] = lsum[r] * scale_[r] + ps;
    }

    // rescale O
    #pragma unroll
    for (int dt = 0; dt < 4; ++dt)
      #pragma unroll
      for (int r = 0; r < 4; ++r) o[dt][r] *= scale_[r];

    // P (C-layout) -> LDS row-major [q][kv], then read back as A-frag
    #pragma unroll
    for (int jt = 0; jt < 2; ++jt)
      #pragma unroll
      for (int r = 0; r < 4; ++r)
        Pb[w][g * 4 + r][jt * 16 + lr] = f2bf(s[jt][r]);

    short8 pa = *reinterpret_cast<const short8*>(&Pb[w][lr][g * 8]);

    // PV: o[dt] += P * V   (V read from Vt rows, contiguous 16B)
    #pragma unroll
    for (int dt = 0; dt < 4; ++dt) {
      short8 bv = *reinterpret_cast<const short8*>(
          Vt + (size_t)(dt * 16 + lr) * N_TOK + kvb + g * 8);
      o[dt] = __builtin_amdgcn_mfma_f32_16x16x32_bf16(pa, bv, o[dt], 0, 0, 0);
    }
  }

  // publish per-wave partials
  #pragma unroll
  for (int dt = 0; dt < 4; ++dt)
    #pragma unroll
    for (int r = 0; r < 4; ++r)
      Opart[w][g * 4 + r][dt * 16 + lr] = o[dt][r];
  if (lr == 0) {
    #pragma unroll
    for (int r = 0; r < 4; ++r) {
      mpart[w][g * 4 + r] = m[r];
      lpart[w][g * 4 + r] = lsum[r];
    }
  }
  __syncthreads();

  // merge 4 wave partials; thread t handles (q = t>>6 + 4k, d = t&63)
  const int d = t & 63;
  for (int qq = (t >> 6); qq < 16; qq += 4) {
    float M = mpart[0][qq];
    M = fmaxf(M, mpart[1][qq]);
    M = fmaxf(M, mpart[2][qq]);
    M = fmaxf(M, mpart[3][qq]);
    float num = 0.0f, den = 0.0f;
    #pragma unroll
    for (int w2 = 0; w2 < 4; ++w2) {
      const float e = exp2f(mpart[w2][qq] - M);
      num += e * Opart[w2][qq][d];
      den += e * lpart[w2][qq];
    }
    out[(size_t)(q0 + qq) * D_OUT + d] = num / den;
  }
}

extern "C" void kernel_launch(void* const* d_in, const int* in_sizes, int n_in,
                              void* d_out, int out_size, void* d_ws, size_t ws_size,
                              hipStream_t stream) {
  const float* X  = (const float*)d_in[0];
  const float* Wq = (const float*)d_in[1];
  const float* Wk = (const float*)d_in[2];
  const float* Wv = (const float*)d_in[3];

  short* Q  = (short*)d_ws;                       // [8192][64] bf16 (pre-scaled)
  short* K  = Q + (size_t)N_TOK * D_OUT;          // [8192][64] bf16
  short* Vt = K + (size_t)N_TOK * D_OUT;          // [64][8192] bf16
  float* out = (float*)d_out;

  hipLaunchKernelGGL(proj_kernel, dim3(N_TOK / 64, 3), dim3(256), 0, stream,
                     X, Wq, Wk, Wv, Q, K, Vt);
  hipLaunchKernelGGL(attn_kernel, dim3(N_TOK / 16), dim3(256), 0, stream,
                     Q, K, Vt, out);
}